// Round 5
// baseline (910.109 us; speedup 1.0000x reference)
//
#include <hip/hip_runtime.h>

// Problem constants (static shapes from setup_inputs / reference)
#define BN   16          // batch
#define TN   60000       // frames
#define FN   80          // features
#define NF4  20          // FN/4 float4 groups
#define SEG  100         // frames per thread (chunk)
#define NSEG 600         // TN/SEG
#define WIN  600         // CMN_WINDOW
#define SBK  6           // WIN/SEG chunks back

// Single fused kernel: one thread per (b, chunk, f4). Each thread
// 1) sums the up-to-600 frames preceding its chunk (init window),
// 2) slides: add leading frame, emit normalized output, drop trailing frame.
// Init re-reads are L2-resident (owners are within +/-120 tids -> same/adjacent
// workgroup on the same XCD). No workspace, no inter-kernel dependency.

__global__ __launch_bounds__(256) void k_cmn(const float* __restrict__ x,
                                             float* __restrict__ out) {
    int tid = blockIdx.x * 256 + threadIdx.x;
    if (tid >= BN * NSEG * NF4) return;
    int f4    = tid % NF4;
    int chunk = (tid / NF4) % NSEG;
    int b     = tid / (NF4 * NSEG);
    size_t base = ((size_t)b * TN + (size_t)chunk * SEG) * FN + f4 * 4;
    const float* xl = x + base;
    float* o = out + base;

    float ls0=0.f,ls1=0.f,ls2=0.f,ls3=0.f,lq0=0.f,lq1=0.f,lq2=0.f,lq3=0.f;

    if (chunk == 0) {
        // t in [0,99]: window fixed [0,100) for every t (we = max(t+1, 100))
        for (int i = 0; i < SEG; ++i) {
            float4 v = *reinterpret_cast<const float4*>(xl + (size_t)i * FN);
            ls0 += v.x; ls1 += v.y; ls2 += v.z; ls3 += v.w;
            lq0 += v.x*v.x; lq1 += v.y*v.y; lq2 += v.z*v.z; lq3 += v.w*v.w;
        }
        const float rn = 1.0f / 100.0f;
        float m0=ls0*rn, m1=ls1*rn, m2=ls2*rn, m3=ls3*rn;
        float i0=rsqrtf(lq0*rn - m0*m0);
        float i1=rsqrtf(lq1*rn - m1*m1);
        float i2=rsqrtf(lq2*rn - m2*m2);
        float i3=rsqrtf(lq3*rn - m3*m3);
        for (int i = 0; i < SEG; ++i) {
            float4 v = *reinterpret_cast<const float4*>(xl + (size_t)i * FN);
            float4 r;
            r.x = (v.x - m0) * i0; r.y = (v.y - m1) * i1;
            r.z = (v.z - m2) * i2; r.w = (v.w - m3) * i3;
            *reinterpret_cast<float4*>(o + (size_t)i * FN) = r;
        }
        return;
    }

    // Init: sum frames [chunk*SEG - initN, chunk*SEG)
    const int initN = (chunk >= SBK) ? WIN : chunk * SEG;
    {
        const float* ip = xl - (size_t)initN * FN;
        for (int i = 0; i < initN; ++i) {
            float4 v = *reinterpret_cast<const float4*>(ip + (size_t)i * FN);
            ls0 += v.x; ls1 += v.y; ls2 += v.z; ls3 += v.w;
            lq0 += v.x*v.x; lq1 += v.y*v.y; lq2 += v.z*v.z; lq3 += v.w*v.w;
        }
    }

    if (chunk < SBK) {
        // t in [100,599]: window [0, t+1), growing n
        for (int i = 0; i < SEG; ++i) {
            float4 v = *reinterpret_cast<const float4*>(xl + (size_t)i * FN);
            ls0 += v.x; ls1 += v.y; ls2 += v.z; ls3 += v.w;
            lq0 += v.x*v.x; lq1 += v.y*v.y; lq2 += v.z*v.z; lq3 += v.w*v.w;
            float rn = 1.0f / (float)(chunk * SEG + i + 1);
            float m0=ls0*rn, m1=ls1*rn, m2=ls2*rn, m3=ls3*rn;
            float4 r;
            r.x = (v.x - m0) * rsqrtf(lq0*rn - m0*m0);
            r.y = (v.y - m1) * rsqrtf(lq1*rn - m1*m1);
            r.z = (v.z - m2) * rsqrtf(lq2*rn - m2*m2);
            r.w = (v.w - m3) * rsqrtf(lq3*rn - m3*m3);
            *reinterpret_cast<float4*>(o + (size_t)i * FN) = r;
        }
    } else {
        // t >= 600: window [t-600, t+1), n = 601.
        // Before iter i the sums cover [t-600, t-1] (600 frames); add leading
        // frame t, use (601 frames), then drop trailing frame t-600.
        const float* xt = xl - (size_t)WIN * FN;
        const float rn = 1.0f / 601.0f;
        for (int i = 0; i < SEG; ++i) {
            float4 v = *reinterpret_cast<const float4*>(xl + (size_t)i * FN);
            float4 w = *reinterpret_cast<const float4*>(xt + (size_t)i * FN);
            ls0 += v.x; ls1 += v.y; ls2 += v.z; ls3 += v.w;
            lq0 += v.x*v.x; lq1 += v.y*v.y; lq2 += v.z*v.z; lq3 += v.w*v.w;
            float m0=ls0*rn, m1=ls1*rn, m2=ls2*rn, m3=ls3*rn;
            float4 r;
            r.x = (v.x - m0) * rsqrtf(lq0*rn - m0*m0);
            r.y = (v.y - m1) * rsqrtf(lq1*rn - m1*m1);
            r.z = (v.z - m2) * rsqrtf(lq2*rn - m2*m2);
            r.w = (v.w - m3) * rsqrtf(lq3*rn - m3*m3);
            *reinterpret_cast<float4*>(o + (size_t)i * FN) = r;
            ls0 -= w.x; ls1 -= w.y; ls2 -= w.z; ls3 -= w.w;
            lq0 -= w.x*w.x; lq1 -= w.y*w.y; lq2 -= w.z*w.z; lq3 -= w.w*w.w;
        }
    }
}

extern "C" void kernel_launch(void* const* d_in, const int* in_sizes, int n_in,
                              void* d_out, int out_size, void* d_ws, size_t ws_size,
                              hipStream_t stream) {
    const float* x = (const float*)d_in[0];
    float* out = (float*)d_out;
    (void)d_ws; (void)ws_size;

    const int n1 = BN * NSEG * NF4;          // 192000 threads
    k_cmn<<<(n1 + 255) / 256, 256, 0, stream>>>(x, out);
}